// Round 6
// baseline (191.002 us; speedup 1.0000x reference)
//
#include <hip/hip_runtime.h>
#include <math.h>

// Problem constants (from reference)
#define N        8192
#define C        128
#define E_TOTAL  262144
#define WPR      256          // bitmap words per row = N/32
#define INV_TEMP 2.0f         // 1/0.5
#define STEPS    10
#define S_ELL    96           // max dedup'd neighbors per row (Poisson(~32) tail safe)
#define S_PAD    104          // ELL leading dim (npad <= 96+7 -> 104 safe, x8 aligned)
#define POS_BLOCKS 2048
#define NEG_BLOCKS 128

// ---- workspace layout (bytes) ----
#define OFF_D       1024                                // float dinv[N]         32 KB
#define OFF_CNT     (OFF_D + 32768)                     // int   cnt[N] (npad)   32 KB
#define OFF_PPOS    (OFF_CNT + 32768)                   // float ppos[2048]      8 KB
#define OFF_PNEG    (OFF_PPOS + POS_BLOCKS * 4)         // float pneg[128]
#define OFF_ELL     (OFF_PNEG + 1024)                   // int2  ell[N*S_PAD]    6.8 MB
#define OFF_BITMAP  (OFF_ELL + N * S_PAD * 8)           // bitmap 8 MB (dead after build_ell)
#define BITMAP_BYTES (N * WPR * 4)
#define OFF_BUFA    OFF_BITMAP                          // bf16 N*C = 2 MB (alias)
#define OFF_BUFB    (OFF_BUFA + N * C * 2)              // bf16 N*C = 2 MB

typedef unsigned int   uint;
typedef unsigned short ushort;

__device__ __forceinline__ float bflo(uint u) { return __uint_as_float(u << 16); }
__device__ __forceinline__ float bfhi(uint u) { return __uint_as_float(u & 0xffff0000u); }
__device__ __forceinline__ ushort f2bf(float f) {   // RNE
    uint u = __float_as_uint(f);
    return (ushort)((u + 0x7fffu + ((u >> 16) & 1u)) >> 16);
}
__device__ __forceinline__ float dot_u(uint a, uint b) {
    return bflo(a) * bflo(b) + bfhi(a) * bfhi(b);
}
__device__ __forceinline__ float log_sigmoid(float z) {
    return fminf(z, 0.0f) - log1pf(expf(-fabsf(z)));
}

__global__ void scatter_edges_kernel(const int* __restrict__ ei,
                                     unsigned int* __restrict__ bm) {
    int e = blockIdx.x * blockDim.x + threadIdx.x;
    if (e >= E_TOTAL) return;
    int s = ei[e];
    int t = ei[E_TOTAL + e];
    atomicOr(&bm[s * WPR + (t >> 5)], 1u << (t & 31));
}

__global__ void degree_kernel(const unsigned int* __restrict__ bm,
                              float* __restrict__ dinv) {
    int row = blockIdx.x;
    int lane = threadIdx.x;  // 64 = one wave
    const unsigned int* p = bm + row * WPR;
    int cnt = 0;
    for (int w = lane; w < WPR; w += 64) cnt += __popc(p[w]);
    for (int off = 32; off > 0; off >>= 1) cnt += __shfl_down(cnt, off, 64);
    if (lane == 0) dinv[row] = 1.0f / sqrtf((float)cnt);
}

// One-time: bitmap -> interleaved ELL pairs (col, wgt) with weight-0 padding to x8
__global__ void build_ell_kernel(const unsigned int* __restrict__ bm,
                                 const float* __restrict__ dinv,
                                 int* __restrict__ cnt,
                                 int2* __restrict__ ell) {
    int row = blockIdx.x;
    int lane = threadIdx.x;  // one wave; each lane owns 4 consecutive words
    const unsigned int* p = bm + row * WPR;
    unsigned int w[4];
    int c = 0;
    for (int i = 0; i < 4; ++i) { w[i] = p[lane * 4 + i]; c += __popc(w[i]); }
    int inc = c;
    for (int off = 1; off < 64; off <<= 1) {
        int v = __shfl_up(inc, off, 64);
        if (lane >= off) inc += v;
    }
    int pos = inc - c;
    int total = __shfl(inc, 63, 64);
    float dr = dinv[row];
    int2* er = ell + row * S_PAD;
    for (int i = 0; i < 4; ++i) {
        unsigned int word = w[i];
        int jbase = (lane * 4 + i) << 5;
        while (word) {
            int b = __ffs(word) - 1;
            word &= word - 1;
            int j = jbase + b;
            if (pos < S_ELL) {
                int2 pr; pr.x = j; pr.y = __float_as_int(dr * dinv[j]);
                er[pos] = pr;
            }
            ++pos;
        }
    }
    int ncap = (total < S_ELL) ? total : S_ELL;
    int npad = (ncap + 7) & ~7;
    if (lane < npad - ncap) {   // pad with weight-0 self entries
        int2 pr; pr.x = row; pr.y = 0;
        er[ncap + lane] = pr;
    }
    if (lane == 0) cnt[row] = npad;
}

// y[row,:] = sum_k wgt * x[col,:]   (fp32 or bf16 input, bf16 output, fp32 accum)
// 256 threads = 4 waves = 4 rows per block; quarter-wave = 1 neighbor row,
// uint4/2xfloat4 = 8 channels per lane. No LDS, no barriers.
__global__ __launch_bounds__(256) void spmm_step_kernel(
        const int* __restrict__ cnt,
        const int2* __restrict__ ell,
        const void* __restrict__ xin,
        ushort* __restrict__ y,
        int first) {
    int wid  = threadIdx.x >> 6;
    int lane = threadIdx.x & 63;
    int row  = blockIdx.x * 4 + wid;
    int npad = cnt[row];
    int qw   = lane >> 4;   // quarter -> neighbor within group of 4
    int l16  = lane & 15;   // covers channels 8*l16 .. 8*l16+7
    const int2* er = ell + row * S_PAD;
    float a0 = 0.f, a1 = 0.f, a2 = 0.f, a3 = 0.f;
    float a4 = 0.f, a5 = 0.f, a6 = 0.f, a7 = 0.f;
    if (first) {
        const float* x = (const float*)xin;
        for (int k = 0; k < npad; k += 8) {
            int2 p0 = er[k + qw];
            int2 p1 = er[k + 4 + qw];
            float w0 = __int_as_float(p0.y);
            float w1 = __int_as_float(p1.y);
            const float* r0 = x + p0.x * C + l16 * 8;
            const float* r1 = x + p1.x * C + l16 * 8;
            float4 u0a = *(const float4*)r0, u0b = *(const float4*)(r0 + 4);
            float4 u1a = *(const float4*)r1, u1b = *(const float4*)(r1 + 4);
            a0 += w0 * u0a.x; a1 += w0 * u0a.y; a2 += w0 * u0a.z; a3 += w0 * u0a.w;
            a4 += w0 * u0b.x; a5 += w0 * u0b.y; a6 += w0 * u0b.z; a7 += w0 * u0b.w;
            a0 += w1 * u1a.x; a1 += w1 * u1a.y; a2 += w1 * u1a.z; a3 += w1 * u1a.w;
            a4 += w1 * u1b.x; a5 += w1 * u1b.y; a6 += w1 * u1b.z; a7 += w1 * u1b.w;
        }
    } else {
        const ushort* x = (const ushort*)xin;
        for (int k = 0; k < npad; k += 8) {
            int2 p0 = er[k + qw];
            int2 p1 = er[k + 4 + qw];
            float w0 = __int_as_float(p0.y);
            float w1 = __int_as_float(p1.y);
            uint4 u0 = *(const uint4*)(x + p0.x * C + l16 * 8);
            uint4 u1 = *(const uint4*)(x + p1.x * C + l16 * 8);
            a0 += w0 * bflo(u0.x); a1 += w0 * bfhi(u0.x);
            a2 += w0 * bflo(u0.y); a3 += w0 * bfhi(u0.y);
            a4 += w0 * bflo(u0.z); a5 += w0 * bfhi(u0.z);
            a6 += w0 * bflo(u0.w); a7 += w0 * bfhi(u0.w);
            a0 += w1 * bflo(u1.x); a1 += w1 * bfhi(u1.x);
            a2 += w1 * bflo(u1.y); a3 += w1 * bfhi(u1.y);
            a4 += w1 * bflo(u1.z); a5 += w1 * bfhi(u1.z);
            a6 += w1 * bflo(u1.w); a7 += w1 * bfhi(u1.w);
        }
    }
    // combine the 4 quarters (xor over lane bits 4,5)
    a0 += __shfl_xor(a0, 16, 64); a0 += __shfl_xor(a0, 32, 64);
    a1 += __shfl_xor(a1, 16, 64); a1 += __shfl_xor(a1, 32, 64);
    a2 += __shfl_xor(a2, 16, 64); a2 += __shfl_xor(a2, 32, 64);
    a3 += __shfl_xor(a3, 16, 64); a3 += __shfl_xor(a3, 32, 64);
    a4 += __shfl_xor(a4, 16, 64); a4 += __shfl_xor(a4, 32, 64);
    a5 += __shfl_xor(a5, 16, 64); a5 += __shfl_xor(a5, 32, 64);
    a6 += __shfl_xor(a6, 16, 64); a6 += __shfl_xor(a6, 32, 64);
    a7 += __shfl_xor(a7, 16, 64); a7 += __shfl_xor(a7, 32, 64);
    if (qw == 0) {
        uint4 o;
        o.x = (uint)f2bf(a0) | ((uint)f2bf(a1) << 16);
        o.y = (uint)f2bf(a2) | ((uint)f2bf(a3) << 16);
        o.z = (uint)f2bf(a4) | ((uint)f2bf(a5) << 16);
        o.w = (uint)f2bf(a6) | ((uint)f2bf(a7) << 16);
        *(uint4*)(y + row * C + l16 * 8) = o;
    }
}

// Merged pos+neg loss: blocks [0,POS_BLOCKS) do pos edges, rest do neg rows.
// 16 items per wave-iteration; 4 lanes per item (32 channels each, 4x uint4).
__global__ void loss_kernel(const ushort* __restrict__ x,
                            const int* __restrict__ ei,
                            const int* __restrict__ ridx,
                            float* __restrict__ ppos,
                            float* __restrict__ pneg) {
    __shared__ float wsum[4];
    int lane = threadIdx.x & 63;
    int g    = lane >> 2;   // group 0..15 -> item within batch
    int q    = lane & 3;    // quarter -> channel slice of 32
    float sum = 0.0f;
    if (blockIdx.x < POS_BLOCKS) {
        int wave = (blockIdx.x * blockDim.x + threadIdx.x) >> 6;
        int nwaves = (POS_BLOCKS * 256) >> 6;
        for (int base = wave * 16; base < E_TOTAL; base += nwaves * 16) {
            int e = base + g;
            int s = ei[e];
            int t = ei[E_TOTAL + e];
            const uint4* ps = (const uint4*)(x + s * C + q * 32);
            const uint4* pt = (const uint4*)(x + t * C + q * 32);
            uint4 s0 = ps[0], s1 = ps[1], s2 = ps[2], s3 = ps[3];
            uint4 t0 = pt[0], t1 = pt[1], t2 = pt[2], t3 = pt[3];
            float p = dot_u(s0.x, t0.x) + dot_u(s0.y, t0.y) + dot_u(s0.z, t0.z) + dot_u(s0.w, t0.w)
                    + dot_u(s1.x, t1.x) + dot_u(s1.y, t1.y) + dot_u(s1.z, t1.z) + dot_u(s1.w, t1.w)
                    + dot_u(s2.x, t2.x) + dot_u(s2.y, t2.y) + dot_u(s2.z, t2.z) + dot_u(s2.w, t2.w)
                    + dot_u(s3.x, t3.x) + dot_u(s3.y, t3.y) + dot_u(s3.z, t3.z) + dot_u(s3.w, t3.w);
            p += __shfl_xor(p, 1, 64);
            p += __shfl_xor(p, 2, 64);
            if (q == 0) sum += log_sigmoid(p * INV_TEMP);
        }
    } else {
        int bi = blockIdx.x - POS_BLOCKS;
        int wave = (bi * blockDim.x + threadIdx.x) >> 6;
        int nwaves = (NEG_BLOCKS * 256) >> 6;
        for (int base = wave * 16; base < N; base += nwaves * 16) {
            int i = base + g;
            int t = ridx[i];
            const uint4* ps = (const uint4*)(x + i * C + q * 32);
            const uint4* pt = (const uint4*)(x + t * C + q * 32);
            uint4 s0 = ps[0], s1 = ps[1], s2 = ps[2], s3 = ps[3];
            uint4 t0 = pt[0], t1 = pt[1], t2 = pt[2], t3 = pt[3];
            float p = dot_u(s0.x, t0.x) + dot_u(s0.y, t0.y) + dot_u(s0.z, t0.z) + dot_u(s0.w, t0.w)
                    + dot_u(s1.x, t1.x) + dot_u(s1.y, t1.y) + dot_u(s1.z, t1.z) + dot_u(s1.w, t1.w)
                    + dot_u(s2.x, t2.x) + dot_u(s2.y, t2.y) + dot_u(s2.z, t2.z) + dot_u(s2.w, t2.w)
                    + dot_u(s3.x, t3.x) + dot_u(s3.y, t3.y) + dot_u(s3.z, t3.z) + dot_u(s3.w, t3.w);
            p += __shfl_xor(p, 1, 64);
            p += __shfl_xor(p, 2, 64);
            if (q == 0) sum += log_sigmoid(-p * INV_TEMP);
        }
    }
    sum += __shfl_xor(sum, 4, 64);
    sum += __shfl_xor(sum, 8, 64);
    sum += __shfl_xor(sum, 16, 64);
    sum += __shfl_xor(sum, 32, 64);
    if (lane == 0) wsum[threadIdx.x >> 6] = sum;
    __syncthreads();
    if (threadIdx.x == 0) {
        float v = (wsum[0] + wsum[1]) + (wsum[2] + wsum[3]);
        if (blockIdx.x < POS_BLOCKS) ppos[blockIdx.x] = v;
        else                         pneg[blockIdx.x - POS_BLOCKS] = v;
    }
}

__global__ void finalize_kernel(const float* __restrict__ ppos,
                                const float* __restrict__ pneg,
                                float* __restrict__ out) {
    __shared__ float red[256];
    int t = threadIdx.x;
    float s = 0.0f;
    for (int i = t; i < POS_BLOCKS; i += 256) s += ppos[i];
    float sn = (t < NEG_BLOCKS) ? pneg[t] : 0.0f;
    red[t] = s * (-1.0f / (float)E_TOTAL) + sn * (-1.0f / (float)N);
    __syncthreads();
    for (int off = 128; off > 0; off >>= 1) {
        if (t < off) red[t] += red[t + off];
        __syncthreads();
    }
    if (t == 0) out[0] = red[0];
}

extern "C" void kernel_launch(void* const* d_in, const int* in_sizes, int n_in,
                              void* d_out, int out_size, void* d_ws, size_t ws_size,
                              hipStream_t stream) {
    (void)in_sizes; (void)n_in; (void)out_size; (void)ws_size;

    const float* emb_in = (const float*)d_in[0];
    const int*   ei     = (const int*)d_in[1];   // (2, E) flattened: src then dst
    const int*   ridx   = (const int*)d_in[2];
    float* out = (float*)d_out;

    char* ws = (char*)d_ws;
    float*        dinv = (float*)(ws + OFF_D);
    int*          cnt  = (int*)(ws + OFF_CNT);
    float*        ppos = (float*)(ws + OFF_PPOS);
    float*        pneg = (float*)(ws + OFF_PNEG);
    int2*         ell  = (int2*)(ws + OFF_ELL);
    unsigned int* bm   = (unsigned int*)(ws + OFF_BITMAP);
    ushort*       bufA = (ushort*)(ws + OFF_BUFA);  // aliases bitmap (dead after build)
    ushort*       bufB = (ushort*)(ws + OFF_BUFB);
    ushort*       buf[2] = {bufA, bufB};

    hipMemsetAsync(bm, 0, BITMAP_BYTES, stream);

    // dedup'd sparse structure (for diffusion)
    scatter_edges_kernel<<<E_TOTAL / 256, 256, 0, stream>>>(ei, bm);
    degree_kernel<<<N, 64, 0, stream>>>(bm, dinv);
    build_ell_kernel<<<N, 64, 0, stream>>>(bm, dinv, cnt, ell);

    // 10 diffusion steps; step 0 reads the pristine fp32 input (cvt fused)
    for (int s = 0; s < STEPS; ++s) {
        const void* xs = (s == 0) ? (const void*)emb_in : (const void*)buf[s & 1];
        ushort* yd = buf[(s + 1) & 1];
        spmm_step_kernel<<<N / 4, 256, 0, stream>>>(cnt, ell, xs, yd, s == 0 ? 1 : 0);
    }
    const ushort* emb = buf[STEPS & 1];

    loss_kernel<<<POS_BLOCKS + NEG_BLOCKS, 256, 0, stream>>>(emb, ei, ridx, ppos, pneg);
    finalize_kernel<<<1, 256, 0, stream>>>(ppos, pneg, out);
}